// Round 1
// baseline (90.497 us; speedup 1.0000x reference)
//
#include <hip/hip_runtime.h>

// Inverse 2-level orthonormal Haar DWT with zero details ==
// 4x4 nearest-neighbor upsample scaled by 1/4.
// in : [B=128, C=3, 128, 128] f32 (flat)
// out: [B=128, C=3, 512, 512] f32 (flat)

__global__ void haar_upsample4_kernel(const float* __restrict__ z,
                                      float* __restrict__ out,
                                      int total /* B*C*128*128 */) {
    const int stride = gridDim.x * blockDim.x;
    for (int t = blockIdx.x * blockDim.x + threadIdx.x; t < total; t += stride) {
        // t = ((bc * 128) + h_in) * 128 + w_in  — input is contiguous in t
        const int w_in = t & 127;
        const int rest = t >> 7;
        const int h_in = rest & 127;
        const int bc   = rest >> 7;          // b*C + c, < 384

        const float val = z[t] * 0.25f;
        const float4 v = make_float4(val, val, val, val);

        // output base: bc*512*512 + (h_in*4)*512 + w_in*4   (floats)
        float4* o = reinterpret_cast<float4*>(
            out + ((size_t)bc * 512 + (size_t)h_in * 4) * 512 + (size_t)w_in * 4);
        // row stride = 512 floats = 128 float4
        o[0]   = v;
        o[128] = v;
        o[256] = v;
        o[384] = v;
    }
}

extern "C" void kernel_launch(void* const* d_in, const int* in_sizes, int n_in,
                              void* d_out, int out_size, void* d_ws, size_t ws_size,
                              hipStream_t stream) {
    const float* z = (const float*)d_in[0];
    float* out = (float*)d_out;
    const int total = in_sizes[0];           // 128 * 3*128*128 = 6,291,456

    const int block = 256;
    int grid = (total + block - 1) / block;  // 24576
    if (grid > 2048) grid = 2048;            // grid-stride the rest

    haar_upsample4_kernel<<<grid, block, 0, stream>>>(z, out, total);
}

// Round 3
// 74.126 us; speedup vs baseline: 1.2208x; 1.2208x over previous
//
#include <hip/hip_runtime.h>

// Inverse 2-level orthonormal Haar DWT with zero details ==
// 4x4 nearest-neighbor upsample scaled by 1/4.
// in : [B=128, C=3, 128, 128] f32 (flat)
// out: [B=128, C=3, 512, 512] f32 (flat)
//
// One thread per output float4 (16B): each aligned 16B chunk of an output row
// is one input pixel repeated 4x. Lane i -> consecutive float4 -> consecutive
// input w: loads 256 B/wave, stores 1 KB/wave, both coalesced and the store
// stream is globally monotone (same shape as the 6.8 TB/s fill kernel).
// Non-temporal stores keep the 403 MB write stream out of L2 so the 25 MB
// input (re-read 4x, once per output row) stays cached.

typedef float f32x4 __attribute__((ext_vector_type(4)));

__global__ void haar_upsample4_kernel(const float* __restrict__ z,
                                      float* __restrict__ out,
                                      int total4 /* out floats / 4 */) {
    const int stride = gridDim.x * blockDim.x;
    for (int i = blockIdx.x * blockDim.x + threadIdx.x; i < total4; i += stride) {
        // i = ((bc * 512) + h) * 128 + w4   (output row = 512 floats = 128 float4)
        const int w4   = i & 127;        // float4 index in row == input w
        const int rest = i >> 7;
        const int h    = rest & 511;
        const int bc   = rest >> 9;      // b*C + c, < 384
        const int h_in = h >> 2;

        const float v = z[(bc << 14) + (h_in << 7) + w4] * 0.25f;
        f32x4 o4 = {v, v, v, v};
        __builtin_nontemporal_store(o4, reinterpret_cast<f32x4*>(out) + i);
    }
}

extern "C" void kernel_launch(void* const* d_in, const int* in_sizes, int n_in,
                              void* d_out, int out_size, void* d_ws, size_t ws_size,
                              hipStream_t stream) {
    const float* z = (const float*)d_in[0];
    float* out = (float*)d_out;
    const int total4 = out_size >> 2;        // 33,554,432 / 4 = 8,388,608

    const int block = 256;
    int grid = (total4 + block - 1) / block; // 32768
    if (grid > 2048) grid = 2048;            // grid-stride: 16 iters/thread

    haar_upsample4_kernel<<<grid, block, 0, stream>>>(z, out, total4);
}